// Round 1
// baseline (13354.324 us; speedup 1.0000x reference)
//
#include <hip/hip_runtime.h>

// RelationalLayerStackModule: 4 layers of {unary-MLP msgs, edge-MLP msgs,
// scatter-sum agg, node-update MLP+LN, graph readout + global MLP+LN, residual}.
// fp32 throughout (no fp32 MFMA on CDNA4 -> vector ALU). Round 0: correctness
// + thread-per-row MLPs with scalar-pipe weight broadcast; atomics for scatter.

#define E 64
#define TWO_E 128
#define BLK 192            // 3 waves; LDS t-buffer 192*65*4 = 49,920 B < 64 KB

// ---------------- zero ----------------
__global__ void k_zero(float4* __restrict__ p, int n4) {
  int i = blockIdx.x * blockDim.x + threadIdx.x;
  if (i < n4) p[i] = make_float4(0.f, 0.f, 0.f, 0.f);
}

// ---------------- unary messages: agg[idx] += MLP(h[idx]) ----------------
__global__ void __launch_bounds__(BLK) k_unary(
    const int* __restrict__ rel_u, const float* __restrict__ h,
    const float* __restrict__ W1, const float* __restrict__ b1,
    const float* __restrict__ W2, const float* __restrict__ b2,
    float* __restrict__ agg, int mu)
{
  __shared__ float tl[BLK * 65];          // per-thread hidden t[64], stride 65 (bank-safe)
  int tid = threadIdx.x;
  int a = blockIdx.x * BLK + tid;
  if (a >= mu) return;                    // no barriers in this kernel
  int idx = rel_u[a];
  const float4* x4 = reinterpret_cast<const float4*>(h + (size_t)idx * E);
  float* t = &tl[tid * 65];

  // layer 1: t = relu(x @ W1 + b1)   (W index is wave-uniform -> s_load)
  #pragma unroll
  for (int jb = 0; jb < 2; ++jb) {
    float acc[32];
    #pragma unroll
    for (int jj = 0; jj < 32; ++jj) acc[jj] = b1[jb * 32 + jj];
    for (int k4 = 0; k4 < 16; ++k4) {
      float4 xv = x4[k4];
      const float* wp = W1 + (k4 * 4) * E + jb * 32;
      #pragma unroll
      for (int u = 0; u < 4; ++u) {
        float xu = (u == 0) ? xv.x : (u == 1) ? xv.y : (u == 2) ? xv.z : xv.w;
        #pragma unroll
        for (int jj = 0; jj < 32; ++jj)
          acc[jj] = fmaf(xu, wp[u * E + jj], acc[jj]);
      }
    }
    #pragma unroll
    for (int jj = 0; jj < 32; ++jj) t[jb * 32 + jj] = fmaxf(acc[jj], 0.f);
  }
  // layer 2 + scatter
  #pragma unroll
  for (int jb = 0; jb < 2; ++jb) {
    float acc[32];
    #pragma unroll
    for (int jj = 0; jj < 32; ++jj) acc[jj] = b2[jb * 32 + jj];
    for (int k = 0; k < E; ++k) {
      float tv = t[k];
      const float* wp = W2 + k * E + jb * 32;
      #pragma unroll
      for (int jj = 0; jj < 32; ++jj) acc[jj] = fmaf(tv, wp[jj], acc[jj]);
    }
    float* ap = agg + (size_t)idx * E + jb * 32;
    #pragma unroll
    for (int jj = 0; jj < 32; ++jj) unsafeAtomicAdd(&ap[jj], acc[jj]);
  }
}

// -------- edge messages: thread = (edge, half). Each half owns 64 of the 128
// hidden units; layer-2 partial sums are combined via the aggregation atomics.
__global__ void __launch_bounds__(BLK) k_edge(
    const int* __restrict__ rel_e, const float* __restrict__ h,
    const float* __restrict__ W1, const float* __restrict__ b1,
    const float* __restrict__ W2, const float* __restrict__ b2,
    float* __restrict__ agg, int me)
{
  __shared__ float tl[BLK * 65];
  int tid = threadIdx.x;
  int e = blockIdx.x * BLK + tid;
  if (e >= me) return;
  int hf = blockIdx.y;                    // uniform per block -> W addrs stay uniform
  int s = rel_e[2 * e], d = rel_e[2 * e + 1];
  const float4* xs4 = reinterpret_cast<const float4*>(h + (size_t)s * E);
  const float4* xd4 = reinterpret_cast<const float4*>(h + (size_t)d * E);
  float* t = &tl[tid * 65];

  // layer 1: t[0..63] = relu(x @ W1[:, hf*64 + ...] + b1[hf*64 + ...])
  #pragma unroll
  for (int jb = 0; jb < 2; ++jb) {
    float acc[32];
    const float* bp = b1 + hf * 64 + jb * 32;
    #pragma unroll
    for (int jj = 0; jj < 32; ++jj) acc[jj] = bp[jj];
    for (int k4 = 0; k4 < 32; ++k4) {     // full 128-wide input [h[s], h[d]]
      float4 xv = (k4 < 16) ? xs4[k4] : xd4[k4 - 16];
      const float* wp = W1 + (k4 * 4) * TWO_E + hf * 64 + jb * 32;
      #pragma unroll
      for (int u = 0; u < 4; ++u) {
        float xu = (u == 0) ? xv.x : (u == 1) ? xv.y : (u == 2) ? xv.z : xv.w;
        #pragma unroll
        for (int jj = 0; jj < 32; ++jj)
          acc[jj] = fmaf(xu, wp[u * TWO_E + jj], acc[jj]);
      }
    }
    #pragma unroll
    for (int jj = 0; jj < 32; ++jj) t[jb * 32 + jj] = fmaxf(acc[jj], 0.f);
  }
  // layer 2 partials over this k-half; bias only from half 0.
  #pragma unroll
  for (int j2b = 0; j2b < 4; ++j2b) {     // 128 outputs in 4 chunks of 32
    float acc[32];
    if (hf == 0) {
      const float* bp = b2 + j2b * 32;
      #pragma unroll
      for (int jj = 0; jj < 32; ++jj) acc[jj] = bp[jj];
    } else {
      #pragma unroll
      for (int jj = 0; jj < 32; ++jj) acc[jj] = 0.f;
    }
    for (int k = 0; k < 64; ++k) {
      float tv = t[k];
      const float* wp = W2 + (hf * 64 + k) * TWO_E + j2b * 32;
      #pragma unroll
      for (int jj = 0; jj < 32; ++jj) acc[jj] = fmaf(tv, wp[jj], acc[jj]);
    }
    int node = (j2b < 2) ? s : d;         // msg[:,0:64] -> arg0, msg[:,64:128] -> arg1
    float* ap = agg + (size_t)node * E + (j2b & 1) * 32;
    #pragma unroll
    for (int jj = 0; jj < 32; ++jj) unsafeAtomicAdd(&ap[jj], acc[jj]);
  }
}

// ---------------- readout: gsum[g] = sum_{n in g} h[n] ----------------
__global__ void k_readout(const float* __restrict__ h, const int* __restrict__ gids,
                          float* __restrict__ gsum, int nn)
{
  int j = threadIdx.x & 63;
  int slot = threadIdx.x >> 6;            // 0..3
  int base = blockIdx.x * 64;
  float acc = 0.f;
  int cur = -1;
  for (int i = 0; i < 16; ++i) {
    int node = base + slot + i * 4;
    if (node < nn) {
      int g = gids[node];
      if (g != cur) {
        if (cur >= 0) unsafeAtomicAdd(&gsum[cur * 64 + j], acc);
        cur = g; acc = 0.f;
      }
      acc += h[(size_t)node * 64 + j];
    }
  }
  if (cur >= 0) unsafeAtomicAdd(&gsum[cur * 64 + j], acc);
}

// ---------------- g = gsum @ Wr + br ----------------
__global__ void k_gproj(const float* __restrict__ gsum, const float* __restrict__ Wr,
                        const float* __restrict__ br, float* __restrict__ g)
{
  int gi = blockIdx.x;
  int j = threadIdx.x;                    // 64 threads
  float acc = br[j];
  for (int k = 0; k < 64; ++k)
    acc = fmaf(gsum[gi * 64 + k], Wr[k * 64 + j], acc);
  g[gi * 64 + j] = acc;
}

// -------- node update: h[n] += LN(MLPu([h,agg])) + LN(MLPg([h,g[gid]])) -----
__global__ void __launch_bounds__(BLK) k_update(
    float* __restrict__ h, const float* __restrict__ agg,
    const float* __restrict__ g, const int* __restrict__ gids,
    const float* __restrict__ Wu1, const float* __restrict__ bu1,
    const float* __restrict__ Wu2, const float* __restrict__ bu2,
    const float* __restrict__ Wg1, const float* __restrict__ bg1,
    const float* __restrict__ Wg2, const float* __restrict__ bg2,
    const float* __restrict__ lnw, const float* __restrict__ lnb,
    int nn)
{
  __shared__ float tl[BLK * 65];
  int tid = threadIdx.x;
  int n = blockIdx.x * BLK + tid;
  if (n >= nn) return;
  float* t = &tl[tid * 65];
  const float4* hx = reinterpret_cast<const float4*>(h + (size_t)n * E);
  const float4* ax = reinterpret_cast<const float4*>(agg + (size_t)n * E);
  int gid = gids[n];
  const float4* gx = reinterpret_cast<const float4*>(g + (size_t)gid * E);

  float nxt[E], gm[E];

  // ===== update MLP, x = [h, agg] =====
  #pragma unroll
  for (int jb = 0; jb < 2; ++jb) {
    float acc[32];
    #pragma unroll
    for (int jj = 0; jj < 32; ++jj) acc[jj] = bu1[jb * 32 + jj];
    for (int k4 = 0; k4 < 32; ++k4) {
      float4 xv = (k4 < 16) ? hx[k4] : ax[k4 - 16];
      const float* wp = Wu1 + (k4 * 4) * E + jb * 32;
      #pragma unroll
      for (int u = 0; u < 4; ++u) {
        float xu = (u == 0) ? xv.x : (u == 1) ? xv.y : (u == 2) ? xv.z : xv.w;
        #pragma unroll
        for (int jj = 0; jj < 32; ++jj) acc[jj] = fmaf(xu, wp[u * E + jj], acc[jj]);
      }
    }
    #pragma unroll
    for (int jj = 0; jj < 32; ++jj) t[jb * 32 + jj] = fmaxf(acc[jj], 0.f);
  }
  #pragma unroll
  for (int jb = 0; jb < 2; ++jb) {
    float acc[32];
    #pragma unroll
    for (int jj = 0; jj < 32; ++jj) acc[jj] = bu2[jb * 32 + jj];
    for (int k = 0; k < E; ++k) {
      float tv = t[k];
      const float* wp = Wu2 + k * E + jb * 32;
      #pragma unroll
      for (int jj = 0; jj < 32; ++jj) acc[jj] = fmaf(tv, wp[jj], acc[jj]);
    }
    #pragma unroll
    for (int jj = 0; jj < 32; ++jj) nxt[jb * 32 + jj] = acc[jj];
  }
  { // LayerNorm(nxt)
    float mu = 0.f;
    #pragma unroll
    for (int j = 0; j < E; ++j) mu += nxt[j];
    mu *= (1.f / E);
    float var = 0.f;
    #pragma unroll
    for (int j = 0; j < E; ++j) { float dm = nxt[j] - mu; var += dm * dm; }
    var *= (1.f / E);
    float rs = rsqrtf(var + 1e-5f);
    #pragma unroll
    for (int j = 0; j < E; ++j) nxt[j] = (nxt[j] - mu) * rs * lnw[j] + lnb[j];
  }

  // ===== global MLP, x = [h, g[gid]] =====
  #pragma unroll
  for (int jb = 0; jb < 2; ++jb) {
    float acc[32];
    #pragma unroll
    for (int jj = 0; jj < 32; ++jj) acc[jj] = bg1[jb * 32 + jj];
    for (int k4 = 0; k4 < 32; ++k4) {
      float4 xv = (k4 < 16) ? hx[k4] : gx[k4 - 16];
      const float* wp = Wg1 + (k4 * 4) * E + jb * 32;
      #pragma unroll
      for (int u = 0; u < 4; ++u) {
        float xu = (u == 0) ? xv.x : (u == 1) ? xv.y : (u == 2) ? xv.z : xv.w;
        #pragma unroll
        for (int jj = 0; jj < 32; ++jj) acc[jj] = fmaf(xu, wp[u * E + jj], acc[jj]);
      }
    }
    #pragma unroll
    for (int jj = 0; jj < 32; ++jj) t[jb * 32 + jj] = fmaxf(acc[jj], 0.f);
  }
  #pragma unroll
  for (int jb = 0; jb < 2; ++jb) {
    float acc[32];
    #pragma unroll
    for (int jj = 0; jj < 32; ++jj) acc[jj] = bg2[jb * 32 + jj];
    for (int k = 0; k < E; ++k) {
      float tv = t[k];
      const float* wp = Wg2 + k * E + jb * 32;
      #pragma unroll
      for (int jj = 0; jj < 32; ++jj) acc[jj] = fmaf(tv, wp[jj], acc[jj]);
    }
    #pragma unroll
    for (int jj = 0; jj < 32; ++jj) gm[jb * 32 + jj] = acc[jj];
  }
  { // LayerNorm(gm)
    float mu = 0.f;
    #pragma unroll
    for (int j = 0; j < E; ++j) mu += gm[j];
    mu *= (1.f / E);
    float var = 0.f;
    #pragma unroll
    for (int j = 0; j < E; ++j) { float dm = gm[j] - mu; var += dm * dm; }
    var *= (1.f / E);
    float rs = rsqrtf(var + 1e-5f);
    #pragma unroll
    for (int j = 0; j < E; ++j) gm[j] = (gm[j] - mu) * rs * lnw[j] + lnb[j];
  }

  // ===== residual: h = h + nxt + gm (in-place; node-local so safe) =====
  float4* ho = reinterpret_cast<float4*>(h + (size_t)n * E);
  #pragma unroll
  for (int j4 = 0; j4 < 16; ++j4) {
    float4 hv = hx[j4];
    float4 o;
    o.x = hv.x + nxt[j4 * 4 + 0] + gm[j4 * 4 + 0];
    o.y = hv.y + nxt[j4 * 4 + 1] + gm[j4 * 4 + 1];
    o.z = hv.z + nxt[j4 * 4 + 2] + gm[j4 * 4 + 2];
    o.w = hv.w + nxt[j4 * 4 + 3] + gm[j4 * 4 + 3];
    ho[j4] = o;
  }
}

extern "C" void kernel_launch(void* const* d_in, const int* in_sizes, int n_in,
                              void* d_out, int out_size, void* d_ws, size_t ws_size,
                              hipStream_t stream) {
  (void)n_in; (void)out_size; (void)ws_size;
  const int*   rel_u = (const int*)d_in[0];
  const int*   rel_e = (const int*)d_in[1];
  const int*   gids  = (const int*)d_in[2];
  // d_in[3] = num_graphs (device scalar; value fixed = 100 by problem spec)
  const float* Wm1_u = (const float*)d_in[4];
  const float* bm1_u = (const float*)d_in[5];
  const float* Wm2_u = (const float*)d_in[6];
  const float* bm2_u = (const float*)d_in[7];
  const float* Wm1_e = (const float*)d_in[8];
  const float* bm1_e = (const float*)d_in[9];
  const float* Wm2_e = (const float*)d_in[10];
  const float* bm2_e = (const float*)d_in[11];
  const float* Wu1   = (const float*)d_in[12];
  const float* bu1   = (const float*)d_in[13];
  const float* Wu2   = (const float*)d_in[14];
  const float* bu2   = (const float*)d_in[15];
  const float* lnw   = (const float*)d_in[16];
  const float* lnb   = (const float*)d_in[17];
  const float* Wr    = (const float*)d_in[18];
  const float* br    = (const float*)d_in[19];
  const float* Wg1   = (const float*)d_in[20];
  const float* bg1   = (const float*)d_in[21];
  const float* Wg2   = (const float*)d_in[22];
  const float* bg2   = (const float*)d_in[23];

  const int MU_ = in_sizes[0];        // 100000
  const int ME_ = in_sizes[1] / 2;    // 200000
  const int NN  = in_sizes[2];        // 50000
  const int GN  = 100;                // num_graphs (fixed by problem)

  float* h    = (float*)d_out;                       // residual stream lives in d_out
  float* agg  = (float*)d_ws;                        // [N*E]
  float* gsum = agg  + (size_t)NN * E;               // [G*E]
  float* g    = gsum + (size_t)GN * E;               // [G*E]
  // ws usage: (N*E + 2*G*E)*4 ≈ 12.9 MB

  { // h = 0 (initial node embeddings)
    int n4 = NN * E / 4;
    k_zero<<<(n4 + 255) / 256, 256, 0, stream>>>((float4*)h, n4);
  }
  for (int l = 0; l < 4; ++l) {
    { // agg = 0, gsum = 0 (contiguous in ws)
      int n4 = (NN * E + GN * E) / 4;
      k_zero<<<(n4 + 255) / 256, 256, 0, stream>>>((float4*)agg, n4);
    }
    k_unary<<<(MU_ + BLK - 1) / BLK, BLK, 0, stream>>>(
        rel_u, h, Wm1_u, bm1_u, Wm2_u, bm2_u, agg, MU_);
    k_edge<<<dim3((ME_ + BLK - 1) / BLK, 2), BLK, 0, stream>>>(
        rel_e, h, Wm1_e, bm1_e, Wm2_e, bm2_e, agg, ME_);
    k_readout<<<(NN + 63) / 64, 256, 0, stream>>>(h, gids, gsum, NN);
    k_gproj<<<GN, 64, 0, stream>>>(gsum, Wr, br, g);
    k_update<<<(NN + BLK - 1) / BLK, BLK, 0, stream>>>(
        h, agg, g, gids,
        Wu1, bu1, Wu2, bu2, Wg1, bg1, Wg2, bg2, lnw, lnb, NN);
  }
}

// Round 2
// 2817.762 us; speedup vs baseline: 4.7393x; 4.7393x over previous
//
#include <hip/hip_runtime.h>

// Round 2: atomic-free scatter. Messages are written to a slot buffer with
// static slot->dst mapping; a per-launch device-built CSR (count/scan/fill)
// lets a gather kernel (wave per node) sum incoming messages coalesced.
// fp32 MLPs with wave-uniform weight addressing (scalar-pipe broadcast).

#define E 64
#define TWO_E 128
#define UBLK 192           // k_unary block (LDS 192*65*4 = 49,920 B)
#define EBLK 64            // edges per k_edge block (128 threads: 2 k-halves)

// ---------------- zero ----------------
__global__ void k_zero(float4* __restrict__ p, int n4) {
  int i = blockIdx.x * blockDim.x + threadIdx.x;
  if (i < n4) p[i] = make_float4(0.f, 0.f, 0.f, 0.f);
}

// ---------------- CSR build ----------------
// slot m in [0,MU): dst = rel_u[m]; slot MU+q, q in [0,2*ME): dst = rel_e[q]
__global__ void k_count(const int* __restrict__ rel_u, const int* __restrict__ rel_e,
                        int* __restrict__ cnt, int mu, int M) {
  int m = blockIdx.x * blockDim.x + threadIdx.x;
  if (m >= M) return;
  int d = (m < mu) ? rel_u[m] : rel_e[m - mu];
  atomicAdd(&cnt[d], 1);
}

__global__ void __launch_bounds__(1024) k_scan(const int* __restrict__ cnt,
                                               int* __restrict__ startp, int nn, int M) {
  __shared__ int ls[1024];
  int t = threadIdx.x;
  const int C = 49;                       // 49*1024 >= 50000
  int c0 = t * C, c1 = min(c0 + C, nn);
  int s = 0;
  for (int i = c0; i < c1; ++i) s += cnt[i];
  ls[t] = s;
  __syncthreads();
  for (int off = 1; off < 1024; off <<= 1) {
    int v = (t >= off) ? ls[t - off] : 0;
    __syncthreads();
    ls[t] += v;
    __syncthreads();
  }
  int run = (t > 0) ? ls[t - 1] : 0;      // exclusive prefix of chunk
  for (int i = c0; i < c1; ++i) { startp[i] = run; run += cnt[i]; }
  if (t == 1023) startp[nn] = M;
}

__global__ void k_copyint(const int* __restrict__ a, int* __restrict__ b, int n) {
  int i = blockIdx.x * blockDim.x + threadIdx.x;
  if (i < n) b[i] = a[i];
}

__global__ void k_fill(const int* __restrict__ rel_u, const int* __restrict__ rel_e,
                       int* __restrict__ cursor, int* __restrict__ idx, int mu, int M) {
  int m = blockIdx.x * blockDim.x + threadIdx.x;
  if (m >= M) return;
  int d = (m < mu) ? rel_u[m] : rel_e[m - mu];
  int p = atomicAdd(&cursor[d], 1);
  idx[p] = m;
}

// ---------------- unary messages: msgbuf[a] = MLP(h[rel_u[a]]) ----------------
__global__ void __launch_bounds__(UBLK) k_unary(
    const int* __restrict__ rel_u, const float* __restrict__ h,
    const float* __restrict__ W1, const float* __restrict__ b1,
    const float* __restrict__ W2, const float* __restrict__ b2,
    float* __restrict__ msgbuf, int mu)
{
  __shared__ float tl[UBLK * 65];
  int tid = threadIdx.x;
  int a = blockIdx.x * UBLK + tid;
  if (a >= mu) return;                    // no barriers here
  int idx = rel_u[a];
  const float4* x4 = reinterpret_cast<const float4*>(h + (size_t)idx * E);
  float* t = &tl[tid * 65];

  #pragma unroll
  for (int jb = 0; jb < 2; ++jb) {
    float acc[32];
    #pragma unroll
    for (int jj = 0; jj < 32; ++jj) acc[jj] = b1[jb * 32 + jj];
    for (int k4 = 0; k4 < 16; ++k4) {
      float4 xv = x4[k4];
      const float* wp = W1 + (k4 * 4) * E + jb * 32;
      #pragma unroll
      for (int u = 0; u < 4; ++u) {
        float xu = (u == 0) ? xv.x : (u == 1) ? xv.y : (u == 2) ? xv.z : xv.w;
        #pragma unroll
        for (int jj = 0; jj < 32; ++jj)
          acc[jj] = fmaf(xu, wp[u * E + jj], acc[jj]);
      }
    }
    #pragma unroll
    for (int jj = 0; jj < 32; ++jj) t[jb * 32 + jj] = fmaxf(acc[jj], 0.f);
  }
  float* mp = msgbuf + (size_t)a * E;
  #pragma unroll
  for (int jb = 0; jb < 2; ++jb) {
    float acc[32];
    #pragma unroll
    for (int jj = 0; jj < 32; ++jj) acc[jj] = b2[jb * 32 + jj];
    for (int k = 0; k < E; ++k) {
      float tv = t[k];
      const float* wp = W2 + k * E + jb * 32;
      #pragma unroll
      for (int jj = 0; jj < 32; ++jj) acc[jj] = fmaf(tv, wp[jj], acc[jj]);
    }
    #pragma unroll
    for (int q = 0; q < 8; ++q)
      reinterpret_cast<float4*>(mp)[jb * 8 + q] =
          make_float4(acc[q * 4], acc[q * 4 + 1], acc[q * 4 + 2], acc[q * 4 + 3]);
  }
}

// -------- edge messages. Block = 64 edges x 2 k-halves (hf wave-uniform).
// Layer-1: thread computes its half's 64 hidden units from full 128-wide x.
// Layer-2: each half computes partial sums over its k-half for all outputs;
// halves combine via LDS; result -> msgbuf slots MU+2e (->s) and MU+2e+1 (->d).
__global__ void __launch_bounds__(128) k_edge(
    const int* __restrict__ rel_e, const float* __restrict__ h,
    const float* __restrict__ W1, const float* __restrict__ b1,
    const float* __restrict__ W2, const float* __restrict__ b2,
    float* __restrict__ msgbuf, int mu, int me)
{
  __shared__ float tl[128 * 65];          // 33,280 B
  __shared__ float comb[EBLK * 65];       // 16,640 B
  int tid = threadIdx.x;
  int lane = tid & 63;
  int hf = __builtin_amdgcn_readfirstlane(tid >> 6);   // wave-uniform 0/1
  int e = blockIdx.x * EBLK + lane;
  bool valid = (e < me);
  int s = 0, d = 0;
  if (valid) { s = rel_e[2 * e]; d = rel_e[2 * e + 1]; }
  const float4* xs4 = reinterpret_cast<const float4*>(h + (size_t)s * E);
  const float4* xd4 = reinterpret_cast<const float4*>(h + (size_t)d * E);
  float* t = &tl[tid * 65];

  if (valid) {
    #pragma unroll
    for (int jb = 0; jb < 2; ++jb) {
      float acc[32];
      const float* bp = b1 + hf * 64 + jb * 32;
      #pragma unroll
      for (int jj = 0; jj < 32; ++jj) acc[jj] = bp[jj];
      for (int k4 = 0; k4 < 16; ++k4) {
        float4 xv = xs4[k4];
        const float* wp = W1 + (k4 * 4) * TWO_E + hf * 64 + jb * 32;
        #pragma unroll
        for (int u = 0; u < 4; ++u) {
          float xu = (u == 0) ? xv.x : (u == 1) ? xv.y : (u == 2) ? xv.z : xv.w;
          #pragma unroll
          for (int jj = 0; jj < 32; ++jj)
            acc[jj] = fmaf(xu, wp[u * TWO_E + jj], acc[jj]);
        }
      }
      for (int k4 = 0; k4 < 16; ++k4) {
        float4 xv = xd4[k4];
        const float* wp = W1 + ((16 + k4) * 4) * TWO_E + hf * 64 + jb * 32;
        #pragma unroll
        for (int u = 0; u < 4; ++u) {
          float xu = (u == 0) ? xv.x : (u == 1) ? xv.y : (u == 2) ? xv.z : xv.w;
          #pragma unroll
          for (int jj = 0; jj < 32; ++jj)
            acc[jj] = fmaf(xu, wp[u * TWO_E + jj], acc[jj]);
        }
      }
      #pragma unroll
      for (int jj = 0; jj < 32; ++jj) t[jb * 32 + jj] = fmaxf(acc[jj], 0.f);
    }
  }

  #pragma unroll
  for (int jh = 0; jh < 2; ++jh) {        // jh=0: out[0:64]->s ; jh=1: out[64:128]->d
    float part[64];
    if (valid) {
      #pragma unroll
      for (int jb = 0; jb < 2; ++jb) {
        const float* bp = b2 + jh * 64 + jb * 32;
        #pragma unroll
        for (int jj = 0; jj < 32; ++jj) part[jb * 32 + jj] = (hf == 0) ? bp[jj] : 0.f;
        for (int k = 0; k < 64; ++k) {
          float tv = t[k];
          const float* wp = W2 + (hf * 64 + k) * TWO_E + jh * 64 + jb * 32;
          #pragma unroll
          for (int jj = 0; jj < 32; ++jj) part[jb * 32 + jj] = fmaf(tv, wp[jj], part[jb * 32 + jj]);
        }
      }
    }
    __syncthreads();                      // everyone done reading t / prev comb
    if (hf == 0 && valid) {
      #pragma unroll
      for (int j = 0; j < 64; ++j) comb[lane * 65 + j] = part[j];
    }
    __syncthreads();
    if (hf == 1 && valid) {
      size_t slot = (size_t)mu + 2 * (size_t)e + jh;
      float4* mp = reinterpret_cast<float4*>(msgbuf + slot * E);
      #pragma unroll
      for (int q = 0; q < 16; ++q) {
        float4 o;
        o.x = comb[lane * 65 + q * 4 + 0] + part[q * 4 + 0];
        o.y = comb[lane * 65 + q * 4 + 1] + part[q * 4 + 1];
        o.z = comb[lane * 65 + q * 4 + 2] + part[q * 4 + 2];
        o.w = comb[lane * 65 + q * 4 + 3] + part[q * 4 + 3];
        mp[q] = o;
      }
    }
  }
}

// ---------------- gather: agg[n] = sum of msgbuf[idx[start[n]..start[n+1])] ----
__global__ void __launch_bounds__(256) k_gather(
    const float* __restrict__ msgbuf, const int* __restrict__ idx,
    const int* __restrict__ startp, float* __restrict__ agg, int nn)
{
  int wave = threadIdx.x >> 6;
  int j = threadIdx.x & 63;
  int n = blockIdx.x * 4 + wave;
  if (n >= nn) return;
  int s0 = startp[n], s1 = startp[n + 1];
  float v = 0.f;
  for (int i = s0; i < s1; ++i) {
    int m = idx[i];
    v += msgbuf[(size_t)m * E + j];
  }
  agg[(size_t)n * E + j] = v;
}

// ---------------- readout: gsum[g] = sum_{n in g} h[n] ----------------
__global__ void k_readout(const float* __restrict__ h, const int* __restrict__ gids,
                          float* __restrict__ gsum, int nn)
{
  int j = threadIdx.x & 63;
  int slot = threadIdx.x >> 6;
  int base = blockIdx.x * 64;
  float acc = 0.f;
  int cur = -1;
  for (int i = 0; i < 16; ++i) {
    int node = base + slot + i * 4;
    if (node < nn) {
      int g = gids[node];
      if (g != cur) {
        if (cur >= 0) unsafeAtomicAdd(&gsum[cur * 64 + j], acc);
        cur = g; acc = 0.f;
      }
      acc += h[(size_t)node * 64 + j];
    }
  }
  if (cur >= 0) unsafeAtomicAdd(&gsum[cur * 64 + j], acc);
}

// ---------------- g = gsum @ Wr + br ----------------
__global__ void k_gproj(const float* __restrict__ gsum, const float* __restrict__ Wr,
                        const float* __restrict__ br, float* __restrict__ g)
{
  int gi = blockIdx.x;
  int j = threadIdx.x;
  float acc = br[j];
  for (int k = 0; k < 64; ++k)
    acc = fmaf(gsum[gi * 64 + k], Wr[k * 64 + j], acc);
  g[gi * 64 + j] = acc;
}

// -------- node update: h[n] += LN(MLPu([h,agg])) + LN(MLPg([h,g[gid]])) -----
__global__ void __launch_bounds__(UBLK) k_update(
    float* __restrict__ h, const float* __restrict__ agg,
    const float* __restrict__ g, const int* __restrict__ gids,
    const float* __restrict__ Wu1, const float* __restrict__ bu1,
    const float* __restrict__ Wu2, const float* __restrict__ bu2,
    const float* __restrict__ Wg1, const float* __restrict__ bg1,
    const float* __restrict__ Wg2, const float* __restrict__ bg2,
    const float* __restrict__ lnw, const float* __restrict__ lnb,
    int nn)
{
  __shared__ float tl[UBLK * 65];
  int tid = threadIdx.x;
  int n = blockIdx.x * UBLK + tid;
  if (n >= nn) return;
  float* t = &tl[tid * 65];
  const float4* hx = reinterpret_cast<const float4*>(h + (size_t)n * E);
  const float4* ax = reinterpret_cast<const float4*>(agg + (size_t)n * E);
  int gid = gids[n];
  const float4* gx = reinterpret_cast<const float4*>(g + (size_t)gid * E);

  float nxt[E], gm[E];

  #pragma unroll
  for (int jb = 0; jb < 2; ++jb) {
    float acc[32];
    #pragma unroll
    for (int jj = 0; jj < 32; ++jj) acc[jj] = bu1[jb * 32 + jj];
    for (int k4 = 0; k4 < 32; ++k4) {
      float4 xv = (k4 < 16) ? hx[k4] : ax[k4 - 16];
      const float* wp = Wu1 + (k4 * 4) * E + jb * 32;
      #pragma unroll
      for (int u = 0; u < 4; ++u) {
        float xu = (u == 0) ? xv.x : (u == 1) ? xv.y : (u == 2) ? xv.z : xv.w;
        #pragma unroll
        for (int jj = 0; jj < 32; ++jj) acc[jj] = fmaf(xu, wp[u * E + jj], acc[jj]);
      }
    }
    #pragma unroll
    for (int jj = 0; jj < 32; ++jj) t[jb * 32 + jj] = fmaxf(acc[jj], 0.f);
  }
  #pragma unroll
  for (int jb = 0; jb < 2; ++jb) {
    float acc[32];
    #pragma unroll
    for (int jj = 0; jj < 32; ++jj) acc[jj] = bu2[jb * 32 + jj];
    for (int k = 0; k < E; ++k) {
      float tv = t[k];
      const float* wp = Wu2 + k * E + jb * 32;
      #pragma unroll
      for (int jj = 0; jj < 32; ++jj) acc[jj] = fmaf(tv, wp[jj], acc[jj]);
    }
    #pragma unroll
    for (int jj = 0; jj < 32; ++jj) nxt[jb * 32 + jj] = acc[jj];
  }
  {
    float mu = 0.f;
    #pragma unroll
    for (int j = 0; j < E; ++j) mu += nxt[j];
    mu *= (1.f / E);
    float var = 0.f;
    #pragma unroll
    for (int j = 0; j < E; ++j) { float dm = nxt[j] - mu; var += dm * dm; }
    var *= (1.f / E);
    float rs = rsqrtf(var + 1e-5f);
    #pragma unroll
    for (int j = 0; j < E; ++j) nxt[j] = (nxt[j] - mu) * rs * lnw[j] + lnb[j];
  }

  #pragma unroll
  for (int jb = 0; jb < 2; ++jb) {
    float acc[32];
    #pragma unroll
    for (int jj = 0; jj < 32; ++jj) acc[jj] = bg1[jb * 32 + jj];
    for (int k4 = 0; k4 < 32; ++k4) {
      float4 xv = (k4 < 16) ? hx[k4] : gx[k4 - 16];
      const float* wp = Wg1 + (k4 * 4) * E + jb * 32;
      #pragma unroll
      for (int u = 0; u < 4; ++u) {
        float xu = (u == 0) ? xv.x : (u == 1) ? xv.y : (u == 2) ? xv.z : xv.w;
        #pragma unroll
        for (int jj = 0; jj < 32; ++jj) acc[jj] = fmaf(xu, wp[u * E + jj], acc[jj]);
      }
    }
    #pragma unroll
    for (int jj = 0; jj < 32; ++jj) t[jb * 32 + jj] = fmaxf(acc[jj], 0.f);
  }
  #pragma unroll
  for (int jb = 0; jb < 2; ++jb) {
    float acc[32];
    #pragma unroll
    for (int jj = 0; jj < 32; ++jj) acc[jj] = bg2[jb * 32 + jj];
    for (int k = 0; k < E; ++k) {
      float tv = t[k];
      const float* wp = Wg2 + k * E + jb * 32;
      #pragma unroll
      for (int jj = 0; jj < 32; ++jj) acc[jj] = fmaf(tv, wp[jj], acc[jj]);
    }
    #pragma unroll
    for (int jj = 0; jj < 32; ++jj) gm[jb * 32 + jj] = acc[jj];
  }
  {
    float mu = 0.f;
    #pragma unroll
    for (int j = 0; j < E; ++j) mu += gm[j];
    mu *= (1.f / E);
    float var = 0.f;
    #pragma unroll
    for (int j = 0; j < E; ++j) { float dm = gm[j] - mu; var += dm * dm; }
    var *= (1.f / E);
    float rs = rsqrtf(var + 1e-5f);
    #pragma unroll
    for (int j = 0; j < E; ++j) gm[j] = (gm[j] - mu) * rs * lnw[j] + lnb[j];
  }

  float4* ho = reinterpret_cast<float4*>(h + (size_t)n * E);
  #pragma unroll
  for (int j4 = 0; j4 < 16; ++j4) {
    float4 hv = hx[j4];
    float4 o;
    o.x = hv.x + nxt[j4 * 4 + 0] + gm[j4 * 4 + 0];
    o.y = hv.y + nxt[j4 * 4 + 1] + gm[j4 * 4 + 1];
    o.z = hv.z + nxt[j4 * 4 + 2] + gm[j4 * 4 + 2];
    o.w = hv.w + nxt[j4 * 4 + 3] + gm[j4 * 4 + 3];
    ho[j4] = o;
  }
}

extern "C" void kernel_launch(void* const* d_in, const int* in_sizes, int n_in,
                              void* d_out, int out_size, void* d_ws, size_t ws_size,
                              hipStream_t stream) {
  (void)n_in; (void)out_size; (void)ws_size;
  const int*   rel_u = (const int*)d_in[0];
  const int*   rel_e = (const int*)d_in[1];
  const int*   gids  = (const int*)d_in[2];
  const float* Wm1_u = (const float*)d_in[4];
  const float* bm1_u = (const float*)d_in[5];
  const float* Wm2_u = (const float*)d_in[6];
  const float* bm2_u = (const float*)d_in[7];
  const float* Wm1_e = (const float*)d_in[8];
  const float* bm1_e = (const float*)d_in[9];
  const float* Wm2_e = (const float*)d_in[10];
  const float* bm2_e = (const float*)d_in[11];
  const float* Wu1   = (const float*)d_in[12];
  const float* bu1   = (const float*)d_in[13];
  const float* Wu2   = (const float*)d_in[14];
  const float* bu2   = (const float*)d_in[15];
  const float* lnw   = (const float*)d_in[16];
  const float* lnb   = (const float*)d_in[17];
  const float* Wr    = (const float*)d_in[18];
  const float* br    = (const float*)d_in[19];
  const float* Wg1   = (const float*)d_in[20];
  const float* bg1   = (const float*)d_in[21];
  const float* Wg2   = (const float*)d_in[22];
  const float* bg2   = (const float*)d_in[23];

  const int MU_ = in_sizes[0];          // 100000
  const int ME_ = in_sizes[1] / 2;      // 200000
  const int NN  = in_sizes[2];          // 50000
  const int GN  = 100;
  const int M   = MU_ + 2 * ME_;        // 500000 message slots

  float* h      = (float*)d_out;
  float* agg    = (float*)d_ws;                          // [N*E]
  float* gsum   = agg + (size_t)NN * E;                  // [G*E]
  float* g      = gsum + (size_t)GN * E;                 // [G*E]
  float* msgbuf = g + (size_t)GN * E;                    // [M*E]  (128 MB)
  int*   cnt    = (int*)(msgbuf + (size_t)M * E);        // [N]
  int*   startp = cnt + NN;                              // [N+1]
  int*   cursor = startp + NN + 1;                       // [N]
  int*   idxl   = cursor + NN;                           // [M]
  // total ws ≈ 143.5 MB

  // h = 0
  {
    int n4 = NN * E / 4;
    k_zero<<<(n4 + 255) / 256, 256, 0, stream>>>((float4*)h, n4);
  }
  // ---- CSR build (once; graph is static across layers) ----
  {
    int n4 = NN / 4;  // cnt zeros (N*4B / 16)
    k_zero<<<(n4 + 255) / 256, 256, 0, stream>>>((float4*)cnt, n4);
  }
  k_count<<<(M + 255) / 256, 256, 0, stream>>>(rel_u, rel_e, cnt, MU_, M);
  k_scan<<<1, 1024, 0, stream>>>(cnt, startp, NN, M);
  k_copyint<<<(NN + 255) / 256, 256, 0, stream>>>(startp, cursor, NN);
  k_fill<<<(M + 255) / 256, 256, 0, stream>>>(rel_u, rel_e, cursor, idxl, MU_, M);

  for (int l = 0; l < 4; ++l) {
    {
      int n4 = GN * E / 4;   // gsum = 0
      k_zero<<<(n4 + 255) / 256, 256, 0, stream>>>((float4*)gsum, n4);
    }
    k_unary<<<(MU_ + UBLK - 1) / UBLK, UBLK, 0, stream>>>(
        rel_u, h, Wm1_u, bm1_u, Wm2_u, bm2_u, msgbuf, MU_);
    k_edge<<<(ME_ + EBLK - 1) / EBLK, 128, 0, stream>>>(
        rel_e, h, Wm1_e, bm1_e, Wm2_e, bm2_e, msgbuf, MU_, ME_);
    k_gather<<<(NN + 3) / 4, 256, 0, stream>>>(msgbuf, idxl, startp, agg, NN);
    k_readout<<<(NN + 63) / 64, 256, 0, stream>>>(h, gids, gsum, NN);
    k_gproj<<<GN, 64, 0, stream>>>(gsum, Wr, br, g);
    k_update<<<(NN + UBLK - 1) / UBLK, UBLK, 0, stream>>>(
        h, agg, g, gids,
        Wu1, bu1, Wu2, bu2, Wg1, bg1, Wg2, bg2, lnw, lnb, NN);
  }
}